// Round 1
// 389.657 us; speedup vs baseline: 1.5271x; 1.5271x over previous
//
#include <hip/hip_runtime.h>

// ---------------------------------------------------------------------------
// MultiDiscreteACTLayer: B=131072 rows, D=256.
// Per row: 8 users x 16 sc logits + 8 heads x 10 pow logits = 208 dots of 256.
// JAX threefry, PARTITIONABLE semantics (jax>=0.4.36 default):
//   split(key,8)[u] = threefry2x32(key, (0, u))          (foldlike, both words)
//   fold_in(key, d) = threefry2x32(key, (0, d))          (both words)
//   random_bits 32-bit, element i: (b1,b2)=tf2(key,(0,i)); bits = b1 ^ b2
// Output (float32): actions (B,16) | logp_sum (B,1) | avail (B,16).
// R9: Phase A moved from fp64 MFMA (78.6 TF roofline, ~190us) to bf16
//     16x16x32 MFMA with LOSSLESS 3-limb decomposition: fp32 = bf16 hi+mid+lo
//     (truncation split, exact), 8 of 9 limb products (drop x2*W2 ~2^-32),
//     magnitude-split accumulators (accM = x0W0, accS = rest) -> logit error
//     ~1e-8, below the reference's own fp32 GEMM rounding (~1e-7).
//     Row-block doubled to 32 rows / 512 threads / 8 waves (halves W L2
//     traffic). W limbs pre-split + fragment-ordered by repack kernel.
//     Layout-robust: A/B share the k-map by construction; C/D labels via
//     runtime MFMA probes. Phases B/C unchanged except 32 rows/block.
// ---------------------------------------------------------------------------

#define B_TOTAL 131072
#define NCOL    208      // 8 users * (16 sc + 10 pow)
#define ROWS    32       // rows per block
#define TINYF   1.17549435e-38f

// W limb plane geometry (shorts): per (tile,chunk) 512, per tile 8*512=4096,
// per plane 13*4096 = 53248. Three planes.
#define WPLANE  53248
#define XB_L    8448     // x limb stride in shorts: 32 rows * 264 pitch
#define XB_P    264      // x row pitch in shorts (16B-aligned, bank-spread)

typedef float f32x4 __attribute__((ext_vector_type(4)));
typedef short short8 __attribute__((ext_vector_type(8)));

#define MFMA_BF16(A,B,C) __builtin_amdgcn_mfma_f32_16x16x32_bf16((A),(B),(C),0,0,0)

struct TF2 { unsigned a, b; };

__host__ __device__ constexpr unsigned rotl_(unsigned x, int r) {
  return (x << r) | (x >> (32 - r));
}

// Threefry-2x32, 20 rounds, exactly as JAX/Random123.
__host__ __device__ constexpr TF2 tf2(unsigned k0, unsigned k1, unsigned x0, unsigned x1) {
  unsigned ks0 = k0, ks1 = k1, ks2 = k0 ^ k1 ^ 0x1BD11BDAu;
  x0 += ks0; x1 += ks1;
  x0 += x1; x1 = rotl_(x1, 13); x1 ^= x0;
  x0 += x1; x1 = rotl_(x1, 15); x1 ^= x0;
  x0 += x1; x1 = rotl_(x1, 26); x1 ^= x0;
  x0 += x1; x1 = rotl_(x1,  6); x1 ^= x0;
  x0 += ks1; x1 += ks2 + 1u;
  x0 += x1; x1 = rotl_(x1, 17); x1 ^= x0;
  x0 += x1; x1 = rotl_(x1, 29); x1 ^= x0;
  x0 += x1; x1 = rotl_(x1, 16); x1 ^= x0;
  x0 += x1; x1 = rotl_(x1, 24); x1 ^= x0;
  x0 += ks2; x1 += ks0 + 2u;
  x0 += x1; x1 = rotl_(x1, 13); x1 ^= x0;
  x0 += x1; x1 = rotl_(x1, 15); x1 ^= x0;
  x0 += x1; x1 = rotl_(x1, 26); x1 ^= x0;
  x0 += x1; x1 = rotl_(x1,  6); x1 ^= x0;
  x0 += ks0; x1 += ks1 + 3u;
  x0 += x1; x1 = rotl_(x1, 17); x1 ^= x0;
  x0 += x1; x1 = rotl_(x1, 29); x1 ^= x0;
  x0 += x1; x1 = rotl_(x1, 16); x1 ^= x0;
  x0 += x1; x1 = rotl_(x1, 24); x1 ^= x0;
  x0 += ks1; x1 += ks2 + 4u;
  x0 += x1; x1 = rotl_(x1, 13); x1 ^= x0;
  x0 += x1; x1 = rotl_(x1, 15); x1 ^= x0;
  x0 += x1; x1 = rotl_(x1, 26); x1 ^= x0;
  x0 += x1; x1 = rotl_(x1,  6); x1 ^= x0;
  x0 += ks2; x1 += ks0 + 5u;
  return TF2{x0, x1};
}

// foldlike derivation from root key (0, 42) — all compile-time constants.
__host__ __device__ constexpr unsigned key_a(unsigned d) { return tf2(0u, 42u, 0u, d).a; }
__host__ __device__ constexpr unsigned key_b(unsigned d) { return tf2(0u, 42u, 0u, d).b; }

constexpr unsigned SK0c[8] = {
  key_a(0), key_a(1), key_a(2), key_a(3), key_a(4), key_a(5), key_a(6), key_a(7)
};
constexpr unsigned SK1c[8] = {
  key_b(0), key_b(1), key_b(2), key_b(3), key_b(4), key_b(5), key_b(6), key_b(7)
};
constexpr unsigned PK0 = key_a(999);
constexpr unsigned PK1 = key_b(999);

// Fast fp64 natural log, positive normal inputs. Range-reduce m to
// [sqrt(1/2), sqrt(2)); atanh series in z=(m-1)/(m+1), terms to 1/13
// (trunc ~3e-12 rel); reciprocal via rcp_f32 seed + 1 fp64 Newton
// (~1.4e-14 rel). Total err ~1e-12 — flip-probability analysis: safe.
__device__ __forceinline__ double dlog(double xd) {
  long long b = __double_as_longlong(xd);
  int e = (int)(b >> 52) - 1023;
  double m = __longlong_as_double((b & 0x000FFFFFFFFFFFFFLL) | 0x3FF0000000000000LL);
  if (m > 1.4142135623730951) { m *= 0.5; e += 1; }
  double mp1 = m + 1.0;
  double r = (double)__builtin_amdgcn_rcpf((float)mp1);
  r = fma(fma(-mp1, r, 1.0), r, r);          // 1 Newton: ~1.4e-14 rel
  double z  = (m - 1.0) * r;
  double z2 = z * z;
  double p = fma(z2, fma(z2, fma(z2, fma(z2, fma(z2,
              1.0/13.0, 1.0/11.0), 1.0/9.0), 1.0/7.0), 1.0/5.0), 1.0/3.0);
  double lm = fma(2.0 * z, z2 * p, 2.0 * z);
  return fma((double)e, 0.6931471805599453, lm);
}

// JAX gumbel from raw bits, fp32 bit-ops replicated; logs in fp64 (dlog).
__device__ __forceinline__ float gumbelf(unsigned bits) {
  float u = __uint_as_float((bits >> 9) | 0x3f800000u) - 1.0f;   // [0,1)
  u = u + TINYF;
  u = fmaxf(TINYF, u);
  double nl = -dlog((double)u);            // in (5.9e-8, 87.4] — normal
  return -(float)dlog(nl);
}

// ---------------------------------------------------------------------------
// Kernel 0: split W_sc (8,256,16) + W_pow (8,256,10) into 3 bf16 limb planes,
// fragment-ordered for the act kernel's per-lane dwordx4 loads:
//   plane l, short index (T*8 + c)*512 + lane*8 + j  holds limb_l of
//   W[k = c*32 + (lane>>4)*8 + j][col = T*16 + (lane&15)],  col = u*26 + n.
// Truncation split: w = l0 + l1 + l2 exactly (fp32 = 3x8 mantissa bits).
// Plus packed bias bp[256] (fp32).
// ---------------------------------------------------------------------------
__global__ void repack_kernel(const float* __restrict__ Wsc, const float* __restrict__ bsc,
                              const float* __restrict__ Wpow, const float* __restrict__ bpow,
                              short* __restrict__ Wb, float* __restrict__ bp) {
  int t = blockIdx.x * 256 + threadIdx.x;   // [0, 53504)
  if (t < 53248) {
    int j    = t & 7;
    int lane = (t >> 3) & 63;
    int c    = (t >> 9) & 7;
    int T    = t >> 12;                     // 0..12
    int k    = c * 32 + (lane >> 4) * 8 + j;
    int col  = T * 16 + (lane & 15);        // < 208
    int u = col / 26, n = col % 26;
    float w = (n < 16) ? Wsc[(u * 256 + k) * 16 + n]
                       : Wpow[(u * 256 + k) * 10 + (n - 16)];
    unsigned b0 = __float_as_uint(w) & 0xFFFF0000u;
    float f1 = w - __uint_as_float(b0);
    unsigned b1 = __float_as_uint(f1) & 0xFFFF0000u;
    float f2 = f1 - __uint_as_float(b1);
    unsigned b2 = __float_as_uint(f2) & 0xFFFF0000u;
    int idx = (T * 8 + c) * 512 + lane * 8 + j;
    Wb[idx]              = (short)(b0 >> 16);
    Wb[WPLANE + idx]     = (short)(b1 >> 16);
    Wb[2 * WPLANE + idx] = (short)(b2 >> 16);
  } else {
    int cc = t - 53248;                     // [0,256)
    float v = 0.f;
    if (cc < NCOL) {
      int u = cc / 26, n = cc % 26;
      v = (n < 16) ? bsc[u * 16 + n] : bpow[u * 10 + (n - 16)];
    }
    bp[cc] = v;
  }
}

// ---------------------------------------------------------------------------
// Main kernel: each block handles 32 consecutive rows, 512 threads / 8 waves.
// Phase A: bf16 MFMA 16x16x32, 3-limb lossless split. 26 (rowhalf,coltile)
//          MFMA-tiles over 8 waves: wave wv -> rh=wv>>2, w4=wv&3; w4 owns 3
//          col-tiles (+1 heavy, rotated by blockIdx&3). 8 limb products per
//          tile per K=32 chunk into accM (x0W0) / accS (small terms).
//          C/D row/col labels resolved by runtime MFMA probes.
// Phase B: threefry+gumbel into LDS (gg aliases xb; constant-key sc loop).
// Phase C: 16 lanes per row; ballot-argmax; no-max-shift softmax (fp32 hw).
// ---------------------------------------------------------------------------
__global__ __launch_bounds__(512, 4) void act_kernel(
    const float* __restrict__ x, const int* __restrict__ avail,
    const short* __restrict__ Wb, const float* __restrict__ bp,
    float* __restrict__ out) {
  __shared__ __align__(16) union SMem {
    short xb[3][ROWS][XB_P];   // Phase A: bf16 limbs of x tile (50688 B)
    float gg[ROWS][NCOL];      // Phase B/C: gumbels (26624 B)
  } sm;
  __shared__ float lg[ROWS][NCOL];

  const int t = threadIdx.x;
  const int b0 = blockIdx.x * ROWS;

  // ---- load x tile (32 rows x 256) as float4, split into bf16 limbs ----
#pragma unroll
  for (int i = 0; i < 4; ++i) {
    int flat = t + 512 * i;            // float4 index, [0,2048)
    int r  = flat >> 6;                // 64 float4 per row
    int kq = flat & 63;
    float4 v = ((const float4*)(x + (size_t)(b0 + r) * 256))[kq];
    unsigned L0[4], L1[4], L2[4];
#pragma unroll
    for (int e = 0; e < 4; ++e) {
      float f = (&v.x)[e];
      unsigned h0 = __float_as_uint(f) & 0xFFFF0000u;
      float f1 = f - __uint_as_float(h0);
      unsigned h1 = __float_as_uint(f1) & 0xFFFF0000u;
      float f2 = f1 - __uint_as_float(h1);
      unsigned h2 = __float_as_uint(f2) & 0xFFFF0000u;
      L0[e] = h0; L1[e] = h1; L2[e] = h2;
    }
    int ks = 4 * kq;
    *(uint2*)&sm.xb[0][r][ks] =
        make_uint2((L0[0] >> 16) | (L0[1] & 0xFFFF0000u),
                   (L0[2] >> 16) | (L0[3] & 0xFFFF0000u));
    *(uint2*)&sm.xb[1][r][ks] =
        make_uint2((L1[0] >> 16) | (L1[1] & 0xFFFF0000u),
                   (L1[2] >> 16) | (L1[3] & 0xFFFF0000u));
    *(uint2*)&sm.xb[2][r][ks] =
        make_uint2((L2[0] >> 16) | (L2[1] & 0xFFFF0000u),
                   (L2[2] >> 16) | (L2[3] & 0xFFFF0000u));
  }
  __syncthreads();

  // ---- Phase A: bf16 MFMA GEMM, 3-limb split, 26 tiles over 8 waves ----
  {
    const int lane64 = t & 63;
    const int wv  = t >> 6;            // wave 0..7
    const int w4  = wv & 3;
    const int rh  = wv >> 2;           // row-half 0/1
    const int q   = lane64 >> 4;       // k-group 0..3
    const int r16 = lane64 & 15;
    const int h   = blockIdx.x & 3;    // which w4 carries the 13th col-tile
    const bool heavy = (w4 == h);
    const int toff = 3 * w4 + ((w4 > h) ? 1 : 0);   // first owned col-tile

    const f32x4 fz = {0.f, 0.f, 0.f, 0.f};
    f32x4 aM0 = fz, aM1 = fz, aM2 = fz, aM3 = fz;
    f32x4 aS0 = fz, aS1 = fz, aS2 = fz, aS3 = fz;

    const short* xr = &sm.xb[0][rh * 16 + r16][0];
    const int wlane = lane64 * 8;

#pragma unroll 1
    for (int c = 0; c < 8; ++c) {
      const int xo = c * 32 + q * 8;
      short8 x0 = *(const short8*)(xr + xo);
      short8 x1 = *(const short8*)(xr + XB_L + xo);
      short8 x2 = *(const short8*)(xr + 2 * XB_L + xo);
      const int wbase = (toff * 8 + c) * 512 + wlane;

#define DO_TILE(WI, AM, AS) do {                                        \
        short8 w0 = *(const short8*)(Wb + (WI));                        \
        short8 w1 = *(const short8*)(Wb + WPLANE + (WI));               \
        short8 w2 = *(const short8*)(Wb + 2 * WPLANE + (WI));           \
        AM = MFMA_BF16(x0, w0, AM);                                     \
        AS = MFMA_BF16(x1, w0, AS);                                     \
        AS = MFMA_BF16(x0, w1, AS);                                     \
        AS = MFMA_BF16(x1, w1, AS);                                     \
        AS = MFMA_BF16(x2, w0, AS);                                     \
        AS = MFMA_BF16(x0, w2, AS);                                     \
        AS = MFMA_BF16(x2, w1, AS);                                     \
        AS = MFMA_BF16(x1, w2, AS);                                     \
      } while (0)

      DO_TILE(wbase,        aM0, aS0);
      DO_TILE(wbase + 4096, aM1, aS1);
      DO_TILE(wbase + 8192, aM2, aS2);
      if (heavy) DO_TILE(wbase + 12288, aM3, aS3);
#undef DO_TILE
    }

    // ---- layout probes: D=i (row labels) and D=j (col labels) ----
    {
      short8 pa = {0, 0, 0, 0, 0, 0, 0, 0};
      short8 pb = {0, 0, 0, 0, 0, 0, 0, 0};
      if (q == 0) {
        pa[0] = (short)(__float_as_uint((float)r16) >> 16);  // bf16(r16), exact
        pb[0] = (short)0x3F80;                               // bf16(1.0)
      }
      f32x4 pr = MFMA_BF16(pa, pb, fz);   // D[i][*] = i
      f32x4 pc = MFMA_BF16(pb, pa, fz);   // D[*][j] = j
#pragma unroll
      for (int r = 0; r < 4; ++r) {
        int i  = ((int)(pr[r] + 0.5f)) & 15;   // x-row label at (lane, reg r)
        int jo = ((int)(pc[r] + 0.5f)) & 15;   // within-tile col label
        int gi = rh * 16 + i;
        int c0 = toff * 16 + jo;               // all owned cols < 208
        lg[gi][c0     ] = aM0[r] + (aS0[r] + bp[c0]);
        lg[gi][c0 + 16] = aM1[r] + (aS1[r] + bp[c0 + 16]);
        lg[gi][c0 + 32] = aM2[r] + (aS2[r] + bp[c0 + 32]);
        if (heavy)
          lg[gi][c0 + 48] = aM3[r] + (aS3[r] + bp[c0 + 48]);
      }
    }
  }
  __syncthreads();   // all xb reads done before gg (aliased) is written

  // ---- Phase B: gumbels (bits = w0 ^ w1) ----
  // sc: one element per thread per user; keys are compile-time constants.
  {
    const int prow = t >> 4;           // 0..31
    const int pn   = t & 15;           // category
    const unsigned cnt = (unsigned)((b0 + prow) * 16 + pn);
    float* grow = &sm.gg[prow][pn];
#pragma unroll
    for (int u = 0; u < 8; ++u) {
      TF2 r = tf2(SK0c[u], SK1c[u], 0u, cnt);
      grow[u * 26] = gumbelf(r.a ^ r.b);
    }
  }
  // pow: 32 rows x 80 = 2560 elements, 5 per thread; magic-mul div.
#pragma unroll
  for (int i = 0; i < 5; ++i) {
    int flat = t + 512 * i;                       // [0, 2560)
    int prw  = (flat * 13108) >> 20;              // flat / 80
    int q80  = flat - prw * 80;
    int hh   = (q80 * 103) >> 10;                 // q80 / 10
    int jj   = q80 - hh * 10;
    unsigned cnt = (unsigned)((b0 + prw) * 80 + q80);
    TF2 r = tf2(PK0, PK1, 0u, cnt);
    sm.gg[prw][hh * 26 + 16 + jj] = gumbelf(r.a ^ r.b);
  }
  __syncthreads();

  // ---- Phase C: sampling. 16 lanes per row. ----
  const int row  = t >> 4;               // 0..31
  const int lane = t & 15;
  const int g16  = (t & 63) >> 4;        // 16-lane group within wave
  const int gb   = b0 + row;
  const int av = avail[gb * 16 + lane];
  int stat = 0;
  float lpsum = 0.0f;
  float my_act = 0.0f;

  // sc scan: 8 users, sequential (sc_stat dependency)
  for (int u = 0; u < 8; ++u) {
    float logit = lg[row][u * 26 + lane];
    float ml = (stat < 2) ? logit : -1e10f;
    float y  = ml + sm.gg[row][u * 26 + lane];
    // max + first-index argmax via ballot
    float vmax = y;
    for (int off = 8; off; off >>= 1) vmax = fmaxf(vmax, __shfl_xor(vmax, off, 16));
    unsigned long long bal = __ballot(y == vmax);
    int idx = __builtin_ctzll((bal >> (g16 * 16)) & 0xFFFFull);
    // softmax denom without max-shift (|logit| small; masked exp -> 0)
    float s = __expf(ml);
    for (int off = 8; off; off >>= 1) s += __shfl_xor(s, off, 16);
    float mlidx = __shfl(ml, idx, 16);
    float lp = mlidx - __logf(s);
    int au = __shfl(av, u, 16);
    if (au > 0) {
      lpsum += lp;
      if (lane == idx) stat += 1;
    }
    if (lane == u) my_act = (au > 0) ? (float)idx : -1.0f;
  }

  // pow heads: independent
  for (int h = 0; h < 8; ++h) {
    bool on = lane < 10;
    float logit = on ? lg[row][h * 26 + 16 + lane] : -3.0e38f;
    float y     = on ? (logit + sm.gg[row][h * 26 + 16 + lane]) : -3.0e38f;
    float vmax = y;
    for (int off = 8; off; off >>= 1) vmax = fmaxf(vmax, __shfl_xor(vmax, off, 16));
    unsigned long long bal = __ballot(y == vmax);
    int idx = __builtin_ctzll((bal >> (g16 * 16)) & 0xFFFFull);
    float s = on ? __expf(logit) : 0.0f;
    for (int off = 8; off; off >>= 1) s += __shfl_xor(s, off, 16);
    float mlidx = __shfl(logit, idx, 16);
    float lp = mlidx - __logf(s);
    int ah = __shfl(av, 8 + h, 16);
    if (ah > 0) lpsum += lp;
    if (lane == 8 + h) my_act = (ah > 0) ? (float)idx : -1.0f;
  }

  // ---- stores (all float32) ----
  out[(size_t)gb * 16 + lane] = my_act;                                // actions
  if (lane == 0) out[(size_t)B_TOTAL * 16 + gb] = lpsum;               // logp sum
  out[(size_t)B_TOTAL * 17 + (size_t)gb * 16 + lane] = (float)av;      // avail
}

extern "C" void kernel_launch(void* const* d_in, const int* in_sizes, int n_in,
                              void* d_out, int out_size, void* d_ws, size_t ws_size,
                              hipStream_t stream) {
  const float* x    = (const float*)d_in[0];
  const int*   av   = (const int*)  d_in[1];
  const float* Wsc  = (const float*)d_in[2];
  const float* bsc  = (const float*)d_in[3];
  const float* Wpow = (const float*)d_in[4];
  const float* bpow = (const float*)d_in[5];
  float* outp = (float*)d_out;

  float* bp = (float*)d_ws;                       // 256 floats
  short* Wb = (short*)((char*)d_ws + 1024);       // 3 * 53248 shorts (~312 KB)

  repack_kernel<<<209, 256, 0, stream>>>(Wsc, bsc, Wpow, bpow, Wb, bp);
  act_kernel<<<B_TOTAL / ROWS, 512, 0, stream>>>(x, av, Wb, bp, outp);
}

// Round 2
// 375.889 us; speedup vs baseline: 1.5830x; 1.0366x over previous
//
#include <hip/hip_runtime.h>

// ---------------------------------------------------------------------------
// MultiDiscreteACTLayer: B=131072 rows, D=256.
// Per row: 8 users x 16 sc logits + 8 heads x 10 pow logits = 208 dots of 256.
// JAX threefry, PARTITIONABLE semantics (jax>=0.4.36 default):
//   split(key,8)[u] = threefry2x32(key, (0, u))          (foldlike, both words)
//   fold_in(key, d) = threefry2x32(key, (0, d))          (both words)
//   random_bits 32-bit, element i: (b1,b2)=tf2(key,(0,i)); bits = b1 ^ b2
// Output (float32): actions (B,16) | logp_sum (B,1) | avail (B,16).
// R10 (from R9's bf16 3-limb GEMM):
//   - Phase A: each wave now computes BOTH row-halves of its col-tiles
//     (13 tiles over 8 waves, rotated 2/1 split) -> W limb L2 traffic halved
//     (2.6 GB -> 1.3 GB), 2x MFMA per chunk hides load latency. Light waves
//     self-balance by reaching the sc-gumbel VALU phase early.
//   - Phase C: LDS-swizzle shuffle reduces replaced with DPP row_ror trees
//     (VALU-forwarded, ~5x less serial latency); avail shuffles replaced by
//     one ballot bitmask; mlidx broadcast via cndmask + DPP-max.
//   - sc gumbels generated straight into registers (generator thread ==
//     consumer thread); only pow gumbels go through LDS (flat [32][80],
//     aliasing the dead x-limb slab).
//   GEMM numerics and fp64 gumbel path unchanged from R9.
// ---------------------------------------------------------------------------

#define B_TOTAL 131072
#define NCOL    208      // 8 users * (16 sc + 10 pow)
#define ROWS    32       // rows per block
#define TINYF   1.17549435e-38f

// W limb plane geometry (shorts): per (tile,chunk) 512, per tile 8*512=4096,
// per plane 13*4096 = 53248. Three planes.
#define WPLANE  53248
#define XB_L    8448     // x limb stride in shorts: 32 rows * 264 pitch
#define XB_P    264      // x row pitch in shorts (16B-aligned, bank-spread)

typedef float f32x4 __attribute__((ext_vector_type(4)));
typedef short short8 __attribute__((ext_vector_type(8)));

#define MFMA_BF16(A,B,C) __builtin_amdgcn_mfma_f32_16x16x32_bf16((A),(B),(C),0,0,0)

// DPP row_ror within 16-lane rows (gfx9+ DPP row = 16 lanes).
// ctrl 0x120|n = row_ror:n. Full exec everywhere -> bound_ctrl false, old=src.
#define ROR16(v, n) __uint_as_float((unsigned)__builtin_amdgcn_update_dpp(     \
    (int)__float_as_uint(v), (int)__float_as_uint(v), 0x120 | (n), 0xF, 0xF, false))

__device__ __forceinline__ float redmax16(float v) {
  v = fmaxf(v, ROR16(v, 8));
  v = fmaxf(v, ROR16(v, 4));
  v = fmaxf(v, ROR16(v, 2));
  v = fmaxf(v, ROR16(v, 1));
  return v;
}
__device__ __forceinline__ float redsum16(float v) {
  v += ROR16(v, 8);
  v += ROR16(v, 4);
  v += ROR16(v, 2);
  v += ROR16(v, 1);
  return v;
}

struct TF2 { unsigned a, b; };

__host__ __device__ constexpr unsigned rotl_(unsigned x, int r) {
  return (x << r) | (x >> (32 - r));
}

// Threefry-2x32, 20 rounds, exactly as JAX/Random123.
__host__ __device__ constexpr TF2 tf2(unsigned k0, unsigned k1, unsigned x0, unsigned x1) {
  unsigned ks0 = k0, ks1 = k1, ks2 = k0 ^ k1 ^ 0x1BD11BDAu;
  x0 += ks0; x1 += ks1;
  x0 += x1; x1 = rotl_(x1, 13); x1 ^= x0;
  x0 += x1; x1 = rotl_(x1, 15); x1 ^= x0;
  x0 += x1; x1 = rotl_(x1, 26); x1 ^= x0;
  x0 += x1; x1 = rotl_(x1,  6); x1 ^= x0;
  x0 += ks1; x1 += ks2 + 1u;
  x0 += x1; x1 = rotl_(x1, 17); x1 ^= x0;
  x0 += x1; x1 = rotl_(x1, 29); x1 ^= x0;
  x0 += x1; x1 = rotl_(x1, 16); x1 ^= x0;
  x0 += x1; x1 = rotl_(x1, 24); x1 ^= x0;
  x0 += ks2; x1 += ks0 + 2u;
  x0 += x1; x1 = rotl_(x1, 13); x1 ^= x0;
  x0 += x1; x1 = rotl_(x1, 15); x1 ^= x0;
  x0 += x1; x1 = rotl_(x1, 26); x1 ^= x0;
  x0 += x1; x1 = rotl_(x1,  6); x1 ^= x0;
  x0 += ks0; x1 += ks1 + 3u;
  x0 += x1; x1 = rotl_(x1, 17); x1 ^= x0;
  x0 += x1; x1 = rotl_(x1, 29); x1 ^= x0;
  x0 += x1; x1 = rotl_(x1, 16); x1 ^= x0;
  x0 += x1; x1 = rotl_(x1, 24); x1 ^= x0;
  x0 += ks1; x1 += ks2 + 4u;
  x0 += x1; x1 = rotl_(x1, 13); x1 ^= x0;
  x0 += x1; x1 = rotl_(x1, 15); x1 ^= x0;
  x0 += x1; x1 = rotl_(x1, 26); x1 ^= x0;
  x0 += x1; x1 = rotl_(x1,  6); x1 ^= x0;
  x0 += ks2; x1 += ks0 + 5u;
  return TF2{x0, x1};
}

// foldlike derivation from root key (0, 42) — all compile-time constants.
__host__ __device__ constexpr unsigned key_a(unsigned d) { return tf2(0u, 42u, 0u, d).a; }
__host__ __device__ constexpr unsigned key_b(unsigned d) { return tf2(0u, 42u, 0u, d).b; }

constexpr unsigned SK0c[8] = {
  key_a(0), key_a(1), key_a(2), key_a(3), key_a(4), key_a(5), key_a(6), key_a(7)
};
constexpr unsigned SK1c[8] = {
  key_b(0), key_b(1), key_b(2), key_b(3), key_b(4), key_b(5), key_b(6), key_b(7)
};
constexpr unsigned PK0 = key_a(999);
constexpr unsigned PK1 = key_b(999);

// Fast fp64 natural log, positive normal inputs. Range-reduce m to
// [sqrt(1/2), sqrt(2)); atanh series in z=(m-1)/(m+1), terms to 1/13
// (trunc ~3e-12 rel); reciprocal via rcp_f32 seed + 1 fp64 Newton
// (~1.4e-14 rel). Total err ~1e-12 — flip-probability analysis: safe.
__device__ __forceinline__ double dlog(double xd) {
  long long b = __double_as_longlong(xd);
  int e = (int)(b >> 52) - 1023;
  double m = __longlong_as_double((b & 0x000FFFFFFFFFFFFFLL) | 0x3FF0000000000000LL);
  if (m > 1.4142135623730951) { m *= 0.5; e += 1; }
  double mp1 = m + 1.0;
  double r = (double)__builtin_amdgcn_rcpf((float)mp1);
  r = fma(fma(-mp1, r, 1.0), r, r);          // 1 Newton: ~1.4e-14 rel
  double z  = (m - 1.0) * r;
  double z2 = z * z;
  double p = fma(z2, fma(z2, fma(z2, fma(z2, fma(z2,
              1.0/13.0, 1.0/11.0), 1.0/9.0), 1.0/7.0), 1.0/5.0), 1.0/3.0);
  double lm = fma(2.0 * z, z2 * p, 2.0 * z);
  return fma((double)e, 0.6931471805599453, lm);
}

// JAX gumbel from raw bits, fp32 bit-ops replicated; logs in fp64 (dlog).
__device__ __forceinline__ float gumbelf(unsigned bits) {
  float u = __uint_as_float((bits >> 9) | 0x3f800000u) - 1.0f;   // [0,1)
  u = u + TINYF;
  u = fmaxf(TINYF, u);
  double nl = -dlog((double)u);            // in (5.9e-8, 87.4] — normal
  return -(float)dlog(nl);
}

// ---------------------------------------------------------------------------
// Kernel 0: split W_sc (8,256,16) + W_pow (8,256,10) into 3 bf16 limb planes,
// fragment-ordered for the act kernel's per-lane dwordx4 loads:
//   plane l, short index (T*8 + c)*512 + lane*8 + j  holds limb_l of
//   W[k = c*32 + (lane>>4)*8 + j][col = T*16 + (lane&15)],  col = u*26 + n.
// Truncation split: w = l0 + l1 + l2 exactly (fp32 = 3x8 mantissa bits).
// Plus packed bias bp[256] (fp32).
// ---------------------------------------------------------------------------
__global__ void repack_kernel(const float* __restrict__ Wsc, const float* __restrict__ bsc,
                              const float* __restrict__ Wpow, const float* __restrict__ bpow,
                              short* __restrict__ Wb, float* __restrict__ bp) {
  int t = blockIdx.x * 256 + threadIdx.x;   // [0, 53504)
  if (t < 53248) {
    int j    = t & 7;
    int lane = (t >> 3) & 63;
    int c    = (t >> 9) & 7;
    int T    = t >> 12;                     // 0..12
    int k    = c * 32 + (lane >> 4) * 8 + j;
    int col  = T * 16 + (lane & 15);        // < 208
    int u = col / 26, n = col % 26;
    float w = (n < 16) ? Wsc[(u * 256 + k) * 16 + n]
                       : Wpow[(u * 256 + k) * 10 + (n - 16)];
    unsigned b0 = __float_as_uint(w) & 0xFFFF0000u;
    float f1 = w - __uint_as_float(b0);
    unsigned b1 = __float_as_uint(f1) & 0xFFFF0000u;
    float f2 = f1 - __uint_as_float(b1);
    unsigned b2 = __float_as_uint(f2) & 0xFFFF0000u;
    int idx = (T * 8 + c) * 512 + lane * 8 + j;
    Wb[idx]              = (short)(b0 >> 16);
    Wb[WPLANE + idx]     = (short)(b1 >> 16);
    Wb[2 * WPLANE + idx] = (short)(b2 >> 16);
  } else {
    int cc = t - 53248;                     // [0,256)
    float v = 0.f;
    if (cc < NCOL) {
      int u = cc / 26, n = cc % 26;
      v = (n < 16) ? bsc[u * 16 + n] : bpow[u * 10 + (n - 16)];
    }
    bp[cc] = v;
  }
}

// 8 limb products (drop x2*W2 ~2^-32): accM = x0W0, accS = 7 small terms.
#define PROD8(X0, X1, X2, W0, W1, W2, AM, AS) do {                      \
    AM = MFMA_BF16(X0, W0, AM);                                         \
    AS = MFMA_BF16(X1, W0, AS);                                         \
    AS = MFMA_BF16(X0, W1, AS);                                         \
    AS = MFMA_BF16(X1, W1, AS);                                         \
    AS = MFMA_BF16(X2, W0, AS);                                         \
    AS = MFMA_BF16(X0, W2, AS);                                         \
    AS = MFMA_BF16(X2, W1, AS);                                         \
    AS = MFMA_BF16(X1, W2, AS);                                         \
  } while (0)

// ---------------------------------------------------------------------------
// Main kernel: each block handles 32 consecutive rows, 512 threads / 8 waves.
// Phase A: bf16 MFMA 16x16x32, 3-limb lossless split. Wave wv owns col-tile
//          tA=(wv+blk)&7 and (if tA<5) tB=8+tA; computes BOTH row-halves per
//          tile (W read once per block). C/D labels via runtime MFMA probes.
// Phase B: sc gumbels -> registers (same thread consumes them in Phase C);
//          pow gumbels -> LDS gpow[32][80] (aliases dead x-limb slab).
// Phase C: 16 lanes per row; DPP row_ror reduce trees; ballot argmax;
//          avail as one ballot bitmask; no-max-shift softmax (fp32 hw).
// ---------------------------------------------------------------------------
__global__ __launch_bounds__(512, 4) void act_kernel(
    const float* __restrict__ x, const int* __restrict__ avail,
    const short* __restrict__ Wb, const float* __restrict__ bp,
    float* __restrict__ out) {
  __shared__ __align__(16) union SMem {
    short xb[3][ROWS][XB_P];   // Phase A: bf16 limbs of x tile (50688 B)
    float gpow[ROWS][80];      // Phase B/C: pow gumbels (10240 B)
  } sm;
  __shared__ float lg[ROWS][NCOL];

  const int t = threadIdx.x;
  const int b0 = blockIdx.x * ROWS;

  // ---- load x tile (32 rows x 256) as float4, split into bf16 limbs ----
#pragma unroll
  for (int i = 0; i < 4; ++i) {
    int flat = t + 512 * i;            // float4 index, [0,2048)
    int r  = flat >> 6;                // 64 float4 per row
    int kq = flat & 63;
    float4 v = ((const float4*)(x + (size_t)(b0 + r) * 256))[kq];
    unsigned L0[4], L1[4], L2[4];
#pragma unroll
    for (int e = 0; e < 4; ++e) {
      float f = (&v.x)[e];
      unsigned h0 = __float_as_uint(f) & 0xFFFF0000u;
      float f1 = f - __uint_as_float(h0);
      unsigned h1 = __float_as_uint(f1) & 0xFFFF0000u;
      float f2 = f1 - __uint_as_float(h1);
      unsigned h2 = __float_as_uint(f2) & 0xFFFF0000u;
      L0[e] = h0; L1[e] = h1; L2[e] = h2;
    }
    int ks = 4 * kq;
    *(uint2*)&sm.xb[0][r][ks] =
        make_uint2((L0[0] >> 16) | (L0[1] & 0xFFFF0000u),
                   (L0[2] >> 16) | (L0[3] & 0xFFFF0000u));
    *(uint2*)&sm.xb[1][r][ks] =
        make_uint2((L1[0] >> 16) | (L1[1] & 0xFFFF0000u),
                   (L1[2] >> 16) | (L1[3] & 0xFFFF0000u));
    *(uint2*)&sm.xb[2][r][ks] =
        make_uint2((L2[0] >> 16) | (L2[1] & 0xFFFF0000u),
                   (L2[2] >> 16) | (L2[3] & 0xFFFF0000u));
  }
  __syncthreads();

  // ---- Phase A: bf16 MFMA GEMM, both row-halves per wave ----
  {
    const int lane64 = t & 63;
    const int wv  = t >> 6;            // wave 0..7
    const int q   = lane64 >> 4;       // k-group 0..3
    const int r16 = lane64 & 15;
    const int tA  = (wv + (blockIdx.x & 7)) & 7;   // col-tile 0..7
    const bool heavy = tA < 5;                     // also owns tB = 8+tA
    const int tB  = 8 + tA;

    const f32x4 fz = {0.f, 0.f, 0.f, 0.f};
    f32x4 mA0 = fz, sA0 = fz, mA1 = fz, sA1 = fz;  // tile A, rh0 / rh1
    f32x4 mB0 = fz, sB0 = fz, mB1 = fz, sB1 = fz;  // tile B

    const short* xr0 = &sm.xb[0][r16][0];
    const short* xr1 = &sm.xb[0][16 + r16][0];
    const int wlane = lane64 * 8;

#pragma unroll 1
    for (int c = 0; c < 8; ++c) {
      const int xo = c * 32 + q * 8;
      short8 a0 = *(const short8*)(xr0 + xo);
      short8 a1 = *(const short8*)(xr0 + XB_L + xo);
      short8 a2 = *(const short8*)(xr0 + 2 * XB_L + xo);
      short8 c0_ = *(const short8*)(xr1 + xo);
      short8 c1_ = *(const short8*)(xr1 + XB_L + xo);
      short8 c2_ = *(const short8*)(xr1 + 2 * XB_L + xo);
      {
        const int wi = (tA * 8 + c) * 512 + wlane;
        short8 w0 = *(const short8*)(Wb + wi);
        short8 w1 = *(const short8*)(Wb + WPLANE + wi);
        short8 w2 = *(const short8*)(Wb + 2 * WPLANE + wi);
        PROD8(a0,  a1,  a2,  w0, w1, w2, mA0, sA0);
        PROD8(c0_, c1_, c2_, w0, w1, w2, mA1, sA1);
      }
      if (heavy) {
        const int wi = (tB * 8 + c) * 512 + wlane;
        short8 w0 = *(const short8*)(Wb + wi);
        short8 w1 = *(const short8*)(Wb + WPLANE + wi);
        short8 w2 = *(const short8*)(Wb + 2 * WPLANE + wi);
        PROD8(a0,  a1,  a2,  w0, w1, w2, mB0, sB0);
        PROD8(c0_, c1_, c2_, w0, w1, w2, mB1, sB1);
      }
    }

    // ---- layout probes: D=i (row labels) and D=j (col labels) ----
    {
      short8 pa = {0, 0, 0, 0, 0, 0, 0, 0};
      short8 pb = {0, 0, 0, 0, 0, 0, 0, 0};
      if (q == 0) {
        pa[0] = (short)(__float_as_uint((float)r16) >> 16);  // bf16(r16), exact
        pb[0] = (short)0x3F80;                               // bf16(1.0)
      }
      f32x4 pr = MFMA_BF16(pa, pb, fz);   // D[i][*] = i
      f32x4 pc = MFMA_BF16(pb, pa, fz);   // D[*][j] = j
#pragma unroll
      for (int r = 0; r < 4; ++r) {
        int i  = ((int)(pr[r] + 0.5f)) & 15;   // x-row label at (lane, reg r)
        int jo = ((int)(pc[r] + 0.5f)) & 15;   // within-tile col label
        int cA = tA * 16 + jo;
        lg[i][cA]      = mA0[r] + (sA0[r] + bp[cA]);
        lg[16 + i][cA] = mA1[r] + (sA1[r] + bp[cA]);
        if (heavy) {
          int cB = tB * 16 + jo;
          lg[i][cB]      = mB0[r] + (sB0[r] + bp[cB]);
          lg[16 + i][cB] = mB1[r] + (sB1[r] + bp[cB]);
        }
      }
    }
  }

  // ---- Phase B (sc): gumbels straight into registers ----
  // Generator thread (t>>4, t&15) == consumer thread in Phase C.
  float gsc[8];
  {
    const int prow = t >> 4;           // 0..31
    const int pn   = t & 15;           // category
    const unsigned cnt = (unsigned)((b0 + prow) * 16 + pn);
#pragma unroll
    for (int u = 0; u < 8; ++u) {
      TF2 r = tf2(SK0c[u], SK1c[u], 0u, cnt);
      gsc[u] = gumbelf(r.a ^ r.b);
    }
  }
  __syncthreads();   // all xb reads done before gpow (aliased) is written

  // ---- Phase B (pow): 32 rows x 80, 5 per thread; flat [row][q80] ----
#pragma unroll
  for (int i = 0; i < 5; ++i) {
    int flat = t + 512 * i;                       // [0, 2560)
    int prw  = (flat * 13108) >> 20;              // flat / 80
    int q80  = flat - prw * 80;
    unsigned cnt = (unsigned)((b0 + prw) * 80 + q80);
    TF2 r = tf2(PK0, PK1, 0u, cnt);
    sm.gpow[prw][q80] = gumbelf(r.a ^ r.b);
  }
  __syncthreads();

  // ---- Phase C: sampling. 16 lanes per row, DPP reduce trees. ----
  const int row  = t >> 4;               // 0..31
  const int lane = t & 15;
  const int g16  = (t & 63) >> 4;        // 16-lane group within wave
  const int shamt = g16 * 16;
  const int gb   = b0 + row;
  const int av = avail[gb * 16 + lane];
  const unsigned avm = (unsigned)((__ballot(av > 0) >> shamt) & 0xFFFFull);
  int stat = 0;
  float lpsum = 0.0f;
  float my_act = 0.0f;

  // sc scan: 8 users, sequential (sc_stat dependency)
#pragma unroll
  for (int u = 0; u < 8; ++u) {
    float logit = lg[row][u * 26 + lane];
    float ml = (stat < 2) ? logit : -1e10f;
    float y  = ml + gsc[u];
    float vmax = redmax16(y);                       // exact max, all lanes
    unsigned long long bal = __ballot(y == vmax);
    int idx = __builtin_ctz((unsigned)((bal >> shamt) & 0xFFFFull));
    float s = redsum16(__expf(ml));                 // softmax denom (no shift)
    float mlidx = redmax16((lane == idx) ? ml : -3.0e38f);  // broadcast ml[idx]
    float lp = mlidx - __logf(s);
    int au = (int)((avm >> u) & 1u);
    if (au) {
      lpsum += lp;
      if (lane == idx) stat += 1;
    }
    if (lane == u) my_act = au ? (float)idx : -1.0f;
  }

  // pow heads: independent
#pragma unroll
  for (int h = 0; h < 8; ++h) {
    bool on = lane < 10;
    float logit = on ? lg[row][h * 26 + 16 + lane] : -3.0e38f;
    float y     = on ? (logit + sm.gpow[row][h * 10 + lane]) : -3.0e38f;
    float vmax = redmax16(y);
    unsigned long long bal = __ballot(y == vmax);
    int idx = __builtin_ctz((unsigned)((bal >> shamt) & 0xFFFFull));
    float s = redsum16(on ? __expf(logit) : 0.0f);
    float mlidx = redmax16((lane == idx) ? logit : -3.0e38f);
    float lp = mlidx - __logf(s);
    int ah = (int)((avm >> (8 + h)) & 1u);
    if (ah) lpsum += lp;
    if (lane == 8 + h) my_act = ah ? (float)idx : -1.0f;
  }

  // ---- stores (all float32) ----
  out[(size_t)gb * 16 + lane] = my_act;                                // actions
  if (lane == 0) out[(size_t)B_TOTAL * 16 + gb] = lpsum;               // logp sum
  out[(size_t)B_TOTAL * 17 + (size_t)gb * 16 + lane] = (float)av;      // avail
}

extern "C" void kernel_launch(void* const* d_in, const int* in_sizes, int n_in,
                              void* d_out, int out_size, void* d_ws, size_t ws_size,
                              hipStream_t stream) {
  const float* x    = (const float*)d_in[0];
  const int*   av   = (const int*)  d_in[1];
  const float* Wsc  = (const float*)d_in[2];
  const float* bsc  = (const float*)d_in[3];
  const float* Wpow = (const float*)d_in[4];
  const float* bpow = (const float*)d_in[5];
  float* outp = (float*)d_out;

  float* bp = (float*)d_ws;                       // 256 floats
  short* Wb = (short*)((char*)d_ws + 1024);       // 3 * 53248 shorts (~312 KB)

  repack_kernel<<<209, 256, 0, stream>>>(Wsc, bsc, Wpow, bpow, Wb, bp);
  act_kernel<<<B_TOTAL / ROWS, 512, 0, stream>>>(x, av, Wb, bp, outp);
}